// Round 15
// baseline (308.082 us; speedup 1.0000x reference)
//
#include <hip/hip_runtime.h>
#include <hip/hip_bf16.h>
#include <math.h>

#define BB   2
#define SS   2048
#define DIM  1024
#define NH   16
#define HD   64
#define MTOT (BB * SS)   // 4096

typedef unsigned short ushortT;
typedef __attribute__((ext_vector_type(8))) short short8v;   // 8 bf16 (4 VGPRs)
typedef __attribute__((ext_vector_type(4))) float float4v;   // 4 fp32 acc
typedef __attribute__((ext_vector_type(16))) float float16v; // 16 fp32 acc (32x32 MFMA)

union FragU { short8v v; unsigned short us[8]; unsigned int u[4]; };

__device__ inline unsigned short f2bf(float x) {             // fp32 -> bf16 RNE
    unsigned u = __builtin_bit_cast(unsigned, x);
    u += 0x7fffu + ((u >> 16) & 1u);
    return (unsigned short)(u >> 16);
}
__device__ inline float bf2f(unsigned short h) {
    unsigned u = ((unsigned)h) << 16;
    return __builtin_bit_cast(float, u);
}
// truncation split: hi = trunc-to-bf16(x), lo = trunc-to-bf16(x - hi)
__device__ inline void split_tr(float x, unsigned short& hi, unsigned short& lo) {
    unsigned u = __builtin_bit_cast(unsigned, x);
    hi = (unsigned short)(u >> 16);
    float hf = __builtin_bit_cast(float, u & 0xffff0000u);
    lo = (unsigned short)(__builtin_bit_cast(unsigned, x - hf) >> 16);
}
__device__ inline void split4(const float4& x, short4& hi, short4& lo) {
    unsigned short h0 = f2bf(x.x), h1 = f2bf(x.y), h2 = f2bf(x.z), h3 = f2bf(x.w);
    hi = make_short4((short)h0, (short)h1, (short)h2, (short)h3);
    lo = make_short4((short)f2bf(x.x - bf2f(h0)), (short)f2bf(x.y - bf2f(h1)),
                     (short)f2bf(x.z - bf2f(h2)), (short)f2bf(x.w - bf2f(h3)));
}
// async global->LDS, 16 B per lane (dest = wave-uniform base + lane*16)
__device__ inline void gld_lds16(const void* g, void* l) {
    __builtin_amdgcn_global_load_lds(
        (const __attribute__((address_space(1))) void*)g,
        (__attribute__((address_space(3))) void*)l, 16, 0, 0);
}
// packed RNE bf16 convert: lo16 = bf16(a), hi16 = bf16(b)
__device__ inline unsigned cvt_pk_bf16(float a, float b) {
    unsigned r;
    asm("v_cvt_pk_bf16_f32 %0, %1, %2" : "=v"(r) : "v"(a), "v"(b));
    return r;
}
// v_permlane32_swap_b32: a' = [a(0:31), b(0:31)], b' = [a(32:63), b(32:63)]
__device__ inline void permlane32_swap(unsigned &a, unsigned &b) {
    asm("v_permlane32_swap_b32 %0, %1" : "+v"(a), "+v"(b));
}

// ---------------------------------------------------------------------------
// fp32 -> bf16 hi/lo elementwise split (X)
// ---------------------------------------------------------------------------
__global__ __launch_bounds__(256) void convert_split_kernel(
    const float* __restrict__ in, ushortT* __restrict__ hi, ushortT* __restrict__ lo, int n4)
{
    int t = blockIdx.x * 256 + threadIdx.x;
    if (t < n4) {
        float4 x = ((const float4*)in)[t];
        short4 h, l; split4(x, h, l);
        ((short4*)hi)[t] = h;
        ((short4*)lo)[t] = l;
    }
}

// ---------------------------------------------------------------------------
// W (1024x1024 fp32, K-major) -> W^T (bf16 hi/lo, N-major rows of K)
// ---------------------------------------------------------------------------
__global__ __launch_bounds__(256) void transpose_split_kernel(
    const float* __restrict__ W0, const float* __restrict__ W1,
    const float* __restrict__ W2, const float* __restrict__ W3,
    ushortT* __restrict__ WtH, ushortT* __restrict__ WtL)
{
    const int z = blockIdx.z;
    const float* __restrict__ W = (z == 0) ? W0 : (z == 1) ? W1 : (z == 2) ? W2 : W3;
    ushortT* H = WtH + (size_t)z * 1024 * 1024;
    ushortT* L = WtL + (size_t)z * 1024 * 1024;

    __shared__ float T[64][65];
    const int k0 = blockIdx.y * 64, n0 = blockIdx.x * 64;
    const int tid = threadIdx.x;
    const int c4 = (tid & 15) * 4;

#pragma unroll
    for (int i = 0; i < 4; i++) {
        int r = (tid >> 4) + 16 * i;
        *(float4*)&T[r][c4] = *(const float4*)(W + (size_t)(k0 + r) * 1024 + n0 + c4);
    }
    __syncthreads();
#pragma unroll
    for (int i = 0; i < 4; i++) {
        int n = (tid >> 4) + 16 * i;
        float4 vv = make_float4(T[c4 + 0][n], T[c4 + 1][n], T[c4 + 2][n], T[c4 + 3][n]);
        short4 h, l; split4(vv, h, l);
        *(short4*)&H[(size_t)(n0 + n) * 1024 + k0 + c4] = h;
        *(short4*)&L[(size_t)(n0 + n) * 1024 + k0 + c4] = l;
    }
}

// ---------------------------------------------------------------------------
// K fp32 (B,S,H*D) -> bf16 hi/lo 64x64 tiles, frag-major for 32x32x16 A-op.
// Frag f = ds*2 + kvt: element (kv = kvt*32 + (lane&31), d = ds*16 + (lane>>5)*8 + j)
// ---------------------------------------------------------------------------
__global__ __launch_bounds__(256) void kv_convert_kernel(
    const float* __restrict__ kw,
    ushortT* __restrict__ KhG, ushortT* __restrict__ KlG)
{
    const int jb = blockIdx.x, bh = blockIdx.y;
    const int b = bh >> 4, h = bh & 15;

    __shared__ float T[64][68];
    const int tid = threadIdx.x;
    const size_t ibase = (size_t)b * SS * DIM + (size_t)h * HD + (size_t)(jb * 64) * DIM;
    const int c4 = (tid & 15) * 4;
#pragma unroll
    for (int i = 0; i < 4; i++) {
        int r = (tid >> 4) + 16 * i;
        *(float4*)&T[r][c4] = *(const float4*)(kw + ibase + (size_t)r * DIM + c4);
    }
    __syncthreads();

    ushortT* oh = KhG + (size_t)(bh * 32 + jb) * 4096;
    ushortT* ol = KlG + (size_t)(bh * 32 + jb) * 4096;

#pragma unroll
    for (int i = 0; i < 2; i++) {
        const int s = tid + i * 256;          // slot 0..511
        const int f = s >> 6;                 // frag 0..7
        const int lane = s & 63;
        const int ds = f >> 1, kvt = f & 1;
        const int kv = kvt * 32 + (lane & 31);
        const int d0 = ds * 16 + (lane >> 5) * 8;
        ushortT hv[8], lv[8];
#pragma unroll
        for (int j = 0; j < 8; j++) split_tr(T[kv][d0 + j], hv[j], lv[j]);
        *(short4*)&oh[s * 8]     = *(short4*)&hv[0];
        *(short4*)&oh[s * 8 + 4] = *(short4*)&hv[4];
        *(short4*)&ol[s * 8]     = *(short4*)&lv[0];
        *(short4*)&ol[s * 8 + 4] = *(short4*)&lv[4];
    }
}

// ---------------------------------------------------------------------------
// Projection GEMM (z=0 Q / z=1 K / z=2 V), 128x128 tile. BK=32 single-buffer
// (32 KB LDS) + (256,3): all 768 blocks co-resident. 1-phase (round-10
// lesson: 2-phase at BK=32 is worse). Two-level XOR swizzle key (r^(r>>2))&3
// on BOTH sides. XCD-chunked remap. Ascending-k accumulation -> bit-identical.
// z==2 stores frag-major 32x32x16 V^T A-op tiles directly.
// Round-6 lesson: K-projection fusion here was net-negative; kv_convert kept.
// ---------------------------------------------------------------------------
__global__ __launch_bounds__(256, 3) void gemm_bt_split_kernel(
    const ushortT* __restrict__ Ah, const ushortT* __restrict__ Al,
    const ushortT* __restrict__ BtH, const ushortT* __restrict__ BtL,
    float* __restrict__ Y0, float* __restrict__ Y1,
    ushortT* __restrict__ VhG, ushortT* __restrict__ VlG)
{
    const int z = blockIdx.z;
    const ushortT* __restrict__ Bh = BtH + (size_t)z * 1024 * 1024;
    const ushortT* __restrict__ Bl = BtL + (size_t)z * 1024 * 1024;

    const int K = 1024, N = 1024;
    // XCD-chunked remap (bijective, grid 8x32 per z; 256%8==0):
    const int wid  = blockIdx.x + (blockIdx.y << 3);
    const int work = ((wid & 7) << 5) + (wid >> 3);
    const int m0 = (work >> 3) * 128;
    const int n0 = (work & 7) * 128;

    __shared__ __align__(16) ushortT AhS[128 * 32];
    __shared__ __align__(16) ushortT AlS[128 * 32];
    __shared__ __align__(16) ushortT BhS[128 * 32];
    __shared__ __align__(16) ushortT BlS[128 * 32];

    const int tid  = threadIdx.x;
    const int wave = tid >> 6, lane = tid & 63;
    const int quad = lane >> 4, l15 = lane & 15;
    const int wm = wave >> 1, wn = wave & 1;
    const int rk = (l15 ^ (l15 >> 2)) & 3;   // read-side swizzle key (= key2(row))

    float4v acc[4][4];
#pragma unroll
    for (int i = 0; i < 4; i++)
#pragma unroll
        for (int j = 0; j < 4; j++) acc[i][j] = (float4v){0.f, 0.f, 0.f, 0.f};

    for (int k0 = 0; k0 < K; k0 += 32) {
        __syncthreads();
#pragma unroll
        for (int i = 0; i < 2; i++) {
            const int s = tid + i * 256;     // slot 0..511: row r = s>>2, blk c = s&3
            const int r = s >> 2;
            // LDS block (r, c) holds global k-block c ^ key2(r)
            const int kk = (((s & 3) ^ (r ^ (r >> 2))) & 3) * 8;
            gld_lds16(Ah + (size_t)(m0 + r) * K + k0 + kk, &AhS[s * 8]);
            gld_lds16(Al + (size_t)(m0 + r) * K + k0 + kk, &AlS[s * 8]);
            gld_lds16(Bh + (size_t)(n0 + r) * K + k0 + kk, &BhS[s * 8]);
            gld_lds16(Bl + (size_t)(n0 + r) * K + k0 + kk, &BlS[s * 8]);
        }
        __syncthreads();

        FragU ah[4], al[4], bh[4], bl[4];
        const int boff = (quad ^ rk) * 8;    // global block quad at slot quad^key2
#pragma unroll
        for (int t = 0; t < 4; t++) {
            const int ra = wm * 64 + t * 16 + l15;   // key2(ra) == rk
            const int rb = wn * 64 + t * 16 + l15;
            ah[t].v = *(const short8v*)&AhS[ra * 32 + boff];
            al[t].v = *(const short8v*)&AlS[ra * 32 + boff];
            bh[t].v = *(const short8v*)&BhS[rb * 32 + boff];
            bl[t].v = *(const short8v*)&BlS[rb * 32 + boff];
        }
#pragma unroll
        for (int mt = 0; mt < 4; mt++)
#pragma unroll
            for (int nt = 0; nt < 4; nt++) {
                acc[mt][nt] = __builtin_amdgcn_mfma_f32_16x16x32_bf16(ah[mt].v, bh[nt].v, acc[mt][nt], 0, 0, 0);
                acc[mt][nt] = __builtin_amdgcn_mfma_f32_16x16x32_bf16(ah[mt].v, bl[nt].v, acc[mt][nt], 0, 0, 0);
                acc[mt][nt] = __builtin_amdgcn_mfma_f32_16x16x32_bf16(al[mt].v, bh[nt].v, acc[mt][nt], 0, 0, 0);
            }
    }

    if (z == 2) {
        // ---- V epilogue: direct frag-major split-bf16 V^T A-op tile store ----
        const int b  = m0 >> 11;
        const int jb = ((m0 & 2047) >> 6) + wm;
        const int h  = (n0 >> 6) + wn;
        const size_t tb = (size_t)((b * 16 + h) * 32 + jb) * 4096;
        ushortT* vh = VhG + tb;
        ushortT* vl = VlG + tb;
#pragma unroll
        for (int mt = 0; mt < 4; mt++)
#pragma unroll
            for (int nt = 0; nt < 4; nt++) {
                const int off = ((((nt >> 1) * 4 + mt) * 64 +
                                  (quad >> 1) * 32 + (nt & 1) * 16 + l15) * 8) +
                                (quad & 1) * 4;
                float4 vv = make_float4(acc[mt][nt][0], acc[mt][nt][1],
                                        acc[mt][nt][2], acc[mt][nt][3]);
                unsigned short h0, l0, h1, l1, h2, l2, h3, l3;
                split_tr(vv.x, h0, l0); split_tr(vv.y, h1, l1);
                split_tr(vv.z, h2, l2); split_tr(vv.w, h3, l3);
                *(short4*)&vh[off] = make_short4((short)h0, (short)h1, (short)h2, (short)h3);
                *(short4*)&vl[off] = make_short4((short)l0, (short)l1, (short)l2, (short)l3);
            }
    } else {
        float* __restrict__ Y = (z == 0) ? Y0 : Y1;
#pragma unroll
        for (int mt = 0; mt < 4; mt++)
#pragma unroll
            for (int r = 0; r < 4; r++) {
                const int row = m0 + wm * 64 + mt * 16 + quad * 4 + r;
                float* yp = Y + (size_t)row * N + n0 + wn * 64 + l15;
#pragma unroll
                for (int nt = 0; nt < 4; nt++)
                    yp[nt * 16] = acc[mt][nt][r];
            }
    }
}

// ---------------------------------------------------------------------------
// BM=64 x BN=128 GEMM for the OUTPUT PROJECTION — round-9 version verbatim
// (BK=64 1-phase + 8-level XOR swizzle + XCD chunk).
// ---------------------------------------------------------------------------
__global__ __launch_bounds__(256, 2) void gemm_bt64_kernel(
    const ushortT* __restrict__ Ah, const ushortT* __restrict__ Al,
    const ushortT* __restrict__ Bh, const ushortT* __restrict__ Bl,
    float* __restrict__ Y)
{
    const int K = 1024, N = 1024;
    const int wid  = blockIdx.x + (blockIdx.y << 3);
    const int work = ((wid & 7) << 6) + (wid >> 3);
    const int m0 = (work >> 3) * 64;
    const int n0 = (work & 7) * 128;

    __shared__ __align__(16) ushortT AhS[64 * 64];
    __shared__ __align__(16) ushortT AlS[64 * 64];
    __shared__ __align__(16) ushortT BhS[128 * 64];
    __shared__ __align__(16) ushortT BlS[128 * 64];

    const int tid  = threadIdx.x;
    const int wave = tid >> 6, lane = tid & 63;
    const int quad = lane >> 4, l15 = lane & 15;
    const int rx = l15 & 7;

    float4v acc[4][2];
#pragma unroll
    for (int i = 0; i < 4; i++)
#pragma unroll
        for (int j = 0; j < 2; j++) acc[i][j] = (float4v){0.f, 0.f, 0.f, 0.f};

    for (int k0 = 0; k0 < K; k0 += 64) {
        __syncthreads();
#pragma unroll
        for (int i = 0; i < 2; i++) {
            const int s = tid + i * 256;
            const int r = s >> 3;
            const int kk = ((s & 7) ^ (r & 7)) * 8;
            gld_lds16(Ah + (size_t)(m0 + r) * K + k0 + kk, &AhS[s * 8]);
            gld_lds16(Al + (size_t)(m0 + r) * K + k0 + kk, &AlS[s * 8]);
        }
#pragma unroll
        for (int i = 0; i < 4; i++) {
            const int s = tid + i * 256;
            const int r = s >> 3;
            const int kk = ((s & 7) ^ (r & 7)) * 8;
            gld_lds16(Bh + (size_t)(n0 + r) * K + k0 + kk, &BhS[s * 8]);
            gld_lds16(Bl + (size_t)(n0 + r) * K + k0 + kk, &BlS[s * 8]);
        }
        __syncthreads();

#pragma unroll
        for (int ks = 0; ks < 2; ks++) {
            FragU ah[4], al[4], bh[2], bl[2];
#pragma unroll
            for (int t = 0; t < 4; t++) {
                const int ra = t * 16 + l15;             // ra&7 == rx
                const int boff = ((ks * 4 + quad) ^ rx) * 8;
                ah[t].v = *(const short8v*)&AhS[ra * 64 + boff];
                al[t].v = *(const short8v*)&AlS[ra * 64 + boff];
            }
#pragma unroll
            for (int t = 0; t < 2; t++) {
                const int rb = wave * 32 + t * 16 + l15; // rb&7 == rx
                const int boff = ((ks * 4 + quad) ^ rx) * 8;
                bh[t].v = *(const short8v*)&BhS[rb * 64 + boff];
                bl[t].v = *(const short8v*)&BlS[rb * 64 + boff];
            }
#pragma unroll
            for (int mt = 0; mt < 4; mt++)
#pragma unroll
                for (int nt = 0; nt < 2; nt++) {
                    acc[mt][nt] = __builtin_amdgcn_mfma_f32_16x16x32_bf16(ah[mt].v, bh[nt].v, acc[mt][nt], 0, 0, 0);
                    acc[mt][nt] = __builtin_amdgcn_mfma_f32_16x16x32_bf16(ah[mt].v, bl[nt].v, acc[mt][nt], 0, 0, 0);
                    acc[mt][nt] = __builtin_amdgcn_mfma_f32_16x16x32_bf16(al[mt].v, bh[nt].v, acc[mt][nt], 0, 0, 0);
                }
        }
    }

#pragma unroll
    for (int mt = 0; mt < 4; mt++)
#pragma unroll
        for (int r = 0; r < 4; r++) {
            const int row = m0 + mt * 16 + quad * 4 + r;
            float* yp = Y + (size_t)row * N + n0 + wave * 32 + l15;
#pragma unroll
            for (int nt = 0; nt < 2; nt++)
                yp[nt * 16] = acc[mt][nt][r];
        }
}

// ---------------------------------------------------------------------------
// MFMA attention, 32x32x16. Round-15 (= round-13 resubmit x2): QBLK 128->64,
// 128-thread blocks (2 waves), grid 32x32 = 1024 blocks, LDS 32 KB single
// K+V buffer -> 4 independent blocks/CU. Same total waves (2048), same
// per-wave math (bit-identical per q-row), but the 8 waves/CU now span 4
// blocks at INDEPENDENT phases: one block's MFMA overlaps another's
// VALU/stage (m114 mechanism) — attacks the measured pipe-serialization
// (MFMA+LDS+VALU summed, not overlapped, at 2 lockstep blocks/CU).
// Single-buffer staging: drain windows filled by sibling blocks (round-3).
// W-form accumulator + XCD-chunked remap (4 heads/XCD) retained.
// NO setprio (round-5). Per-step division is SEMANTIC (round-2); W-form
// carries it exactly: W_t = (al_t/l_{t-1})W_{t-1} + P_t V_t, O = W/l_T.
// ---------------------------------------------------------------------------
__global__ __launch_bounds__(128, 2) void attn_mfma_kernel(
    const float* __restrict__ q,
    const ushortT* __restrict__ KhG, const ushortT* __restrict__ KlG,
    const ushortT* __restrict__ VhG, const ushortT* __restrict__ VlG,
    ushortT* __restrict__ Oh, ushortT* __restrict__ Ol)
{
    // layout (ushort units): K {hi 4096, lo 4096} @0, V {hi, lo} @8192
    __shared__ __align__(16) ushortT SMEM[16384];   // 32 KiB

    const int tid  = threadIdx.x;                   // 0..127
    const int wave = tid >> 6, lane = tid & 63;
    const int l31 = lane & 31, hi5 = lane >> 5;
    // XCD-chunked remap: 1024 works = 8 XCD x 128; XCD x owns heads [4x,4x+4)
    const int wid  = blockIdx.x + (blockIdx.y << 5);
    const int work = ((wid & 7) << 7) + (wid >> 3);
    const int qx = work & 31;
    const int bh = work >> 5;
    const int b = bh >> 4, h = bh & 15;
    const size_t base = (size_t)b * SS * DIM + (size_t)h * HD;
    const int qs0 = qx * 64 + wave * 32;
    const int lane8 = lane * 8;

    ushortT* Kb = SMEM;          // Kh @0, Kl @4096
    ushortT* Vb = SMEM + 8192;   // Vh @0, Vl @4096 (relative)

    // ---- Q fragments (B-op: n = q = l31, k = d = ds*16 + hi5*8 + j) ----
    const float qscale = 0.125f * 1.4426950408889634f;
    FragU Qh[4], Ql[4];
    {
        const int qrow = qs0 + l31;
#pragma unroll
        for (int ds = 0; ds < 4; ds++) {
            const float* p0 = q + base + (size_t)qrow * DIM + ds * 16 + hi5 * 8;
            float4 a = *(const float4*)(p0);
            float4 c = *(const float4*)(p0 + 4);
            float e[8] = {a.x, a.y, a.z, a.w, c.x, c.y, c.z, c.w};
#pragma unroll
            for (int j = 0; j < 8; j++) {
                float x = e[j] * qscale;
                unsigned short hs = f2bf(x);
                Qh[ds].us[j] = hs;
                Ql[ds].us[j] = f2bf(x - bf2f(hs));
            }
        }
    }

    // W accumulators (= l_run * O): tile dt covers d = dt*32 + row, col q = l31
    float16v Oacc[2];
#pragma unroll
    for (int dt = 0; dt < 2; dt++)
        Oacc[dt] = (float16v){0.f,0.f,0.f,0.f,0.f,0.f,0.f,0.f,
                              0.f,0.f,0.f,0.f,0.f,0.f,0.f,0.f};

    float m_run = -INFINITY;
    float l_run = 0.f;
    float inv_prev = 1.0f;   // 1/l_{t-1}; arbitrary at t=0 (al=0 kills it)

    // stage K and V tile t into the single buffers (128 threads x 4 issues
    // per array cover the 512 16B-slots of each 8KB half)
    auto stage = [&](int t) {
        const size_t tb = (size_t)(bh * 32 + t) * 4096;
#pragma unroll
        for (int i = 0; i < 4; i++) {
            const int s = tid + i * 128;   // 0..511
            gld_lds16(KhG + tb + s * 8, &Kb[s * 8]);
            gld_lds16(KlG + tb + s * 8, &Kb[4096 + s * 8]);
            gld_lds16(VhG + tb + s * 8, &Vb[s * 8]);
            gld_lds16(VlG + tb + s * 8, &Vb[4096 + s * 8]);
        }
    };

    auto qk = [&](float16v (&st)[2]) {
        const ushortT* KhS = Kb;
        const ushortT* KlS = Kb + 4096;
#pragma unroll
        for (int t = 0; t < 2; t++)
            st[t] = (float16v){0.f,0.f,0.f,0.f,0.f,0.f,0.f,0.f,
                               0.f,0.f,0.f,0.f,0.f,0.f,0.f,0.f};
#pragma unroll
        for (int ds = 0; ds < 4; ds++) {
            FragU kh0, kl0, kh1, kl1;
            kh0.v = *(const short8v*)&KhS[(ds * 2 + 0) * 512 + lane8];
            kl0.v = *(const short8v*)&KlS[(ds * 2 + 0) * 512 + lane8];
            kh1.v = *(const short8v*)&KhS[(ds * 2 + 1) * 512 + lane8];
            kl1.v = *(const short8v*)&KlS[(ds * 2 + 1) * 512 + lane8];
            st[0] = __builtin_amdgcn_mfma_f32_32x32x16_bf16(kh0.v, Qh[ds].v, st[0], 0, 0, 0);
            st[0] = __builtin_amdgcn_mfma_f32_32x32x16_bf16(kh0.v, Ql[ds].v, st[0], 0, 0, 0);
            st[0] = __builtin_amdgcn_mfma_f32_32x32x16_bf16(kl0.v, Qh[ds].v, st[0], 0, 0, 0);
            st[1] = __builtin_amdgcn_mfma_f32_32x32x16_bf16(kh1.v, Qh[ds].v, st[1], 0, 0, 0);
            st[1] = __builtin_amdgcn_mfma_f32_32x32x16_bf16(kh1.v, Ql[ds].v, st[1], 0, 0, 0);
            st[1] = __builtin_amdgcn_mfma_f32_32x32x16_bf16(kl1.v, Qh[ds].v, st[1], 0, 0, 0);
        }
    };

    auto finish = [&](float16v (&st)[2]) {
        const ushortT* VhS = Vb;
        const ushortT* VlS = Vb + 4096;
        float wscale;
        {
            float g[8];
#pragma unroll
            for (int t = 0; t < 2; t++)
#pragma unroll
                for (int i = 0; i < 4; i++)
                    g[t * 4 + i] = fmaxf(fmaxf(st[t][4 * i], st[t][4 * i + 1]),
                                         fmaxf(st[t][4 * i + 2], st[t][4 * i + 3]));
            float vmax = fmaxf(fmaxf(fmaxf(g[0], g[1]), fmaxf(g[2], g[3])),
                               fmaxf(fmaxf(g[4], g[5]), fmaxf(g[6], g[7])));
            vmax = fmaxf(vmax, __shfl_xor(vmax, 32, 64));
            const float mn = fmaxf(m_run, vmax);
            const float al = __builtin_amdgcn_exp2f(m_run - mn);   // 0 on first iter

            float ssum = 0.f;
#pragma unroll
            for (int t = 0; t < 2; t++)
#pragma unroll
                for (int r = 0; r < 16; r++) {
                    const float p = __builtin_amdgcn_exp2f(st[t][r] - mn);
                    st[t][r] = p;
                    ssum += p;
                }
            ssum += __shfl_xor(ssum, 32, 64);
            const float ln = al * l_run + ssum;
            wscale = al * inv_prev;          // al / l_{t-1}: carries prev division
            inv_prev = __builtin_amdgcn_rcpf(ln);
            m_run = mn;
            l_run = ln;
        }

#pragma unroll
        for (int dt = 0; dt < 2; dt++)
#pragma unroll
            for (int r = 0; r < 16; r++)
                Oacc[dt][r] *= wscale;

#pragma unroll
        for (int kvs = 0; kvs < 4; kvs++) {
            const int kvt = kvs >> 1;
            const int R = (kvs & 1) * 8;
            float p0 = st[kvt][R + 0], p1 = st[kvt][R + 1];
            float p2 = st[kvt][R + 2], p3 = st[kvt][R + 3];
            float p4 = st[kvt][R + 4], p5 = st[kvt][R + 5];
            float p6 = st[kvt][R + 6], p7 = st[kvt][R + 7];
            unsigned X0 = cvt_pk_bf16(p0, p1), X1 = cvt_pk_bf16(p2, p3);
            unsigned Y0 = cvt_pk_bf16(p4, p5), Y1 = cvt_pk_bf16(p6, p7);
            float e0 = p0 - __builtin_bit_cast(float, X0 << 16);
            float e1 = p1 - __builtin_bit_cast(float, X0 & 0xffff0000u);
            float e2 = p2 - __builtin_bit_cast(float, X1 << 16);
            float e3 = p3 - __builtin_bit_cast(float, X1 & 0xffff0000u);
            float e4 = p4 - __builtin_bit_cast(float, Y0 << 16);
            float e5 = p5 - __builtin_bit_cast(float, Y0 & 0xffff0000u);
            float e6 = p6 - __builtin_bit_cast(float, Y1 << 16);
            float e7 = p7 - __builtin_bit_cast(float, Y1 & 0xffff0000u);
            unsigned Z0 = cvt_pk_bf16(e0, e1), Z1 = cvt_pk_bf16(e2, e3);
            unsigned W0 = cvt_pk_bf16(e4, e5), W1 = cvt_pk_bf16(e6, e7);
            permlane32_swap(X0, Y0);
            permlane32_swap(X1, Y1);
            permlane32_swap(Z0, W0);
            permlane32_swap(Z1, W1);
            FragU Phf, Plf;
            Phf.u[0] = X0; Phf.u[1] = X1; Phf.u[2] = Y0; Phf.u[3] = Y1;
            Plf.u[0] = Z0; Plf.u[1] = Z1; Plf.u[2] = W0; Plf.u[3] = W1;

#pragma unroll
            for (int dt = 0; dt < 2; dt++) {
                FragU vh, vl;
                vh.v = *(const short8v*)&VhS[(dt * 4 + kvs) * 512 + lane8];
                vl.v = *(const short8v*)&VlS[(dt * 4 + kvs) * 512 + lane8];
                Oacc[dt] = __builtin_amdgcn_mfma_f32_32x32x16_bf16(vh.v, Phf.v, Oacc[dt], 0, 0, 0);
                Oacc[dt] = __builtin_amdgcn_mfma_f32_32x32x16_bf16(vl.v, Phf.v, Oacc[dt], 0, 0, 0);
                Oacc[dt] = __builtin_amdgcn_mfma_f32_32x32x16_bf16(vh.v, Plf.v, Oacc[dt], 0, 0, 0);
            }
        }
    };

    float16v st[2];

    stage(0);
    __syncthreads();                 // vmcnt drain + publish tile 0

    for (int jb = 0; jb < 32; jb++) {
        qk(st);
        finish(st);
        __syncthreads();             // all 2 waves done reading K/V (WAR)
        if (jb < 31) {
            stage(jb + 1);
            __syncthreads();         // vmcnt drain + publish next tile
        }
    }

    // ---- deferred final division: O = W * (1/l_last) ----
#pragma unroll
    for (int dt = 0; dt < 2; dt++)
#pragma unroll
        for (int r = 0; r < 16; r++)
            Oacc[dt][r] *= inv_prev;

    // ---- epilogue: transpose O^T per tile via wave-local LDS (reuse SMEM),
    //      split-bf16 coalesced store ----  (2 waves x 1056 f32 = 8.4 KB)
    float* EP = ((float*)SMEM) + wave * 1056;   // [32 q][33 f32] per wave
    const int qq = lane >> 1, dh = (lane & 1) * 16;
#pragma unroll
    for (int dt = 0; dt < 2; dt++) {
#pragma unroll
        for (int g = 0; g < 4; g++) {
            float4 wv = make_float4(Oacc[dt][4 * g + 0], Oacc[dt][4 * g + 1],
                                    Oacc[dt][4 * g + 2], Oacc[dt][4 * g + 3]);
            *(float4*)&EP[l31 * 33 + g * 8 + hi5 * 4] = wv;
        }
        // wave-local region: lgkmcnt orders write->read, no barrier
        float vals[16];
#pragma unroll
        for (int k4 = 0; k4 < 4; k4++)
            *(float4*)&vals[k4 * 4] = *(const float4*)&EP[qq * 33 + dh + k4 * 4];

        unsigned ho[8], lo8[8];
#pragma unroll
        for (int kk = 0; kk < 8; kk++) {
            unsigned short h0, l0, h1, l1;
            split_tr(vals[2 * kk], h0, l0);
            split_tr(vals[2 * kk + 1], h1, l1);
            ho[kk]  = (unsigned)h0 | ((unsigned)h1 << 16);
            lo8[kk] = (unsigned)l0 | ((unsigned)l1 << 16);
        }
        const int qrow = qs0 + qq;
        const size_t off = (size_t)(b * SS + qrow) * DIM + h * HD + dt * 32 + dh;
        *(uint4*)&Oh[off]     = make_uint4(ho[0], ho[1], ho[2], ho[3]);
        *(uint4*)&Oh[off + 8] = make_uint4(ho[4], ho[5], ho[6], ho[7]);
        *(uint4*)&Ol[off]     = make_uint4(lo8[0], lo8[1], lo8[2], lo8[3]);
        *(uint4*)&Ol[off + 8] = make_uint4(lo8[4], lo8[5], lo8[6], lo8[7]);
    }
}

// ---------------------------------------------------------------------------
extern "C" void kernel_launch(void* const* d_in, const int* in_sizes, int n_in,
                              void* d_out, int out_size, void* d_ws, size_t ws_size,
                              hipStream_t stream)
{
    const float* x  = (const float*)d_in[0];
    const float* Wq = (const float*)d_in[1];
    const float* Wk = (const float*)d_in[2];
    const float* Wv = (const float*)d_in[3];
    const float* Wo = (const float*)d_in[4];
    float* out = (float*)d_out;

    char* w = (char*)d_ws;
    float*   qw  = (float*)(w);                        // 16 MB
    float*   kw  = (float*)(w + ((size_t)16 << 20));   // 16 MB (later Oh/Ol)
    ushortT* VhG = (ushortT*)(w + ((size_t)32 << 20)); // 8 MB (V frag tiles, from GEMM)
    ushortT* VlG = (ushortT*)(w + ((size_t)40 << 20)); // 8 MB
    ushortT* XhS = (ushortT*)(w + ((size_t)48 << 20)); // 8 MB
    ushortT* XlS = (ushortT*)(w + ((size_t)56 << 20)); // 8 MB
    ushortT* WtH = (ushortT*)(w + ((size_t)64 << 20)); // 8 MB (4 matrices)
    ushortT* WtL = (ushortT*)(w + ((size_t)72 << 20)); // 8 MB
    ushortT* KhG = (ushortT*)(w + ((size_t)80 << 20)); // 8 MB
    ushortT* KlG = (ushortT*)(w + ((size_t)88 << 20)); // 8 MB  -> 96 MB total
    ushortT* OhS = (ushortT*)kw;                       // reuse after kv_convert
    ushortT* OlS = (ushortT*)(w + ((size_t)24 << 20));

    dim3 blk(256);
    const int n4 = MTOT * DIM / 4;

    // split X -> bf16 hi/lo; transpose+split all four W
    convert_split_kernel<<<dim3(n4 / 256), blk, 0, stream>>>(x, XhS, XlS, n4);
    transpose_split_kernel<<<dim3(16, 16, 4), blk, 0, stream>>>(Wq, Wk, Wv, Wo, WtH, WtL);

    // Q/K/V projections; z==2 (V) emits frag-major split tiles directly
    gemm_bt_split_kernel<<<dim3(8, 32, 3), blk, 0, stream>>>(
        XhS, XlS, WtH, WtL, qw, kw, VhG, VlG);

    // K -> frag-major split tiles (32x32x16 A-op layout)
    kv_convert_kernel<<<dim3(32, 32), blk, 0, stream>>>(kw, KhG, KlG);

    // attention: 1024 blocks x 128 threads (QBLK=64), 4 blocks/CU
    attn_mfma_kernel<<<dim3(32, 32), dim3(128), 0, stream>>>(
        qw, KhG, KlG, VhG, VlG, OhS, OlS);

    // output projection: BM=64 tile, BK=64 1-phase (round-9 verified)
    gemm_bt64_kernel<<<dim3(8, 64), blk, 0, stream>>>(
        OhS, OlS, WtH + (size_t)3 * 1024 * 1024, WtL + (size_t)3 * 1024 * 1024,
        out);
}

// Round 16
// 281.883 us; speedup vs baseline: 1.0929x; 1.0929x over previous
//
#include <hip/hip_runtime.h>
#include <hip/hip_bf16.h>
#include <math.h>

#define BB   2
#define SS   2048
#define DIM  1024
#define NH   16
#define HD   64
#define MTOT (BB * SS)   // 4096

typedef unsigned short ushortT;
typedef __attribute__((ext_vector_type(8))) short short8v;   // 8 bf16 (4 VGPRs)
typedef __attribute__((ext_vector_type(4))) float float4v;   // 4 fp32 acc
typedef __attribute__((ext_vector_type(16))) float float16v; // 16 fp32 acc (32x32 MFMA)

union FragU { short8v v; unsigned short us[8]; unsigned int u[4]; };

__device__ inline unsigned short f2bf(float x) {             // fp32 -> bf16 RNE
    unsigned u = __builtin_bit_cast(unsigned, x);
    u += 0x7fffu + ((u >> 16) & 1u);
    return (unsigned short)(u >> 16);
}
__device__ inline float bf2f(unsigned short h) {
    unsigned u = ((unsigned)h) << 16;
    return __builtin_bit_cast(float, u);
}
// truncation split: hi = trunc-to-bf16(x), lo = trunc-to-bf16(x - hi)
__device__ inline void split_tr(float x, unsigned short& hi, unsigned short& lo) {
    unsigned u = __builtin_bit_cast(unsigned, x);
    hi = (unsigned short)(u >> 16);
    float hf = __builtin_bit_cast(float, u & 0xffff0000u);
    lo = (unsigned short)(__builtin_bit_cast(unsigned, x - hf) >> 16);
}
__device__ inline void split4(const float4& x, short4& hi, short4& lo) {
    unsigned short h0 = f2bf(x.x), h1 = f2bf(x.y), h2 = f2bf(x.z), h3 = f2bf(x.w);
    hi = make_short4((short)h0, (short)h1, (short)h2, (short)h3);
    lo = make_short4((short)f2bf(x.x - bf2f(h0)), (short)f2bf(x.y - bf2f(h1)),
                     (short)f2bf(x.z - bf2f(h2)), (short)f2bf(x.w - bf2f(h3)));
}
// async global->LDS, 16 B per lane (dest = wave-uniform base + lane*16)
__device__ inline void gld_lds16(const void* g, void* l) {
    __builtin_amdgcn_global_load_lds(
        (const __attribute__((address_space(1))) void*)g,
        (__attribute__((address_space(3))) void*)l, 16, 0, 0);
}
// packed RNE bf16 convert: lo16 = bf16(a), hi16 = bf16(b)
__device__ inline unsigned cvt_pk_bf16(float a, float b) {
    unsigned r;
    asm("v_cvt_pk_bf16_f32 %0, %1, %2" : "=v"(r) : "v"(a), "v"(b));
    return r;
}
// v_permlane32_swap_b32: a' = [a(0:31), b(0:31)], b' = [a(32:63), b(32:63)]
__device__ inline void permlane32_swap(unsigned &a, unsigned &b) {
    asm("v_permlane32_swap_b32 %0, %1" : "+v"(a), "+v"(b));
}

// ---------------------------------------------------------------------------
// fp32 -> bf16 hi/lo elementwise split (X)
// ---------------------------------------------------------------------------
__global__ __launch_bounds__(256) void convert_split_kernel(
    const float* __restrict__ in, ushortT* __restrict__ hi, ushortT* __restrict__ lo, int n4)
{
    int t = blockIdx.x * 256 + threadIdx.x;
    if (t < n4) {
        float4 x = ((const float4*)in)[t];
        short4 h, l; split4(x, h, l);
        ((short4*)hi)[t] = h;
        ((short4*)lo)[t] = l;
    }
}

// ---------------------------------------------------------------------------
// W (1024x1024 fp32, K-major) -> W^T (bf16 hi/lo, N-major rows of K)
// ---------------------------------------------------------------------------
__global__ __launch_bounds__(256) void transpose_split_kernel(
    const float* __restrict__ W0, const float* __restrict__ W1,
    const float* __restrict__ W2, const float* __restrict__ W3,
    ushortT* __restrict__ WtH, ushortT* __restrict__ WtL)
{
    const int z = blockIdx.z;
    const float* __restrict__ W = (z == 0) ? W0 : (z == 1) ? W1 : (z == 2) ? W2 : W3;
    ushortT* H = WtH + (size_t)z * 1024 * 1024;
    ushortT* L = WtL + (size_t)z * 1024 * 1024;

    __shared__ float T[64][65];
    const int k0 = blockIdx.y * 64, n0 = blockIdx.x * 64;
    const int tid = threadIdx.x;
    const int c4 = (tid & 15) * 4;

#pragma unroll
    for (int i = 0; i < 4; i++) {
        int r = (tid >> 4) + 16 * i;
        *(float4*)&T[r][c4] = *(const float4*)(W + (size_t)(k0 + r) * 1024 + n0 + c4);
    }
    __syncthreads();
#pragma unroll
    for (int i = 0; i < 4; i++) {
        int n = (tid >> 4) + 16 * i;
        float4 vv = make_float4(T[c4 + 0][n], T[c4 + 1][n], T[c4 + 2][n], T[c4 + 3][n]);
        short4 h, l; split4(vv, h, l);
        *(short4*)&H[(size_t)(n0 + n) * 1024 + k0 + c4] = h;
        *(short4*)&L[(size_t)(n0 + n) * 1024 + k0 + c4] = l;
    }
}

// ---------------------------------------------------------------------------
// K fp32 (B,S,H*D) -> bf16 hi/lo 64x64 tiles, frag-major for 32x32x16 A-op.
// Frag f = ds*2 + kvt: element (kv = kvt*32 + (lane&31), d = ds*16 + (lane>>5)*8 + j)
// ---------------------------------------------------------------------------
__global__ __launch_bounds__(256) void kv_convert_kernel(
    const float* __restrict__ kw,
    ushortT* __restrict__ KhG, ushortT* __restrict__ KlG)
{
    const int jb = blockIdx.x, bh = blockIdx.y;
    const int b = bh >> 4, h = bh & 15;

    __shared__ float T[64][68];
    const int tid = threadIdx.x;
    const size_t ibase = (size_t)b * SS * DIM + (size_t)h * HD + (size_t)(jb * 64) * DIM;
    const int c4 = (tid & 15) * 4;
#pragma unroll
    for (int i = 0; i < 4; i++) {
        int r = (tid >> 4) + 16 * i;
        *(float4*)&T[r][c4] = *(const float4*)(kw + ibase + (size_t)r * DIM + c4);
    }
    __syncthreads();

    ushortT* oh = KhG + (size_t)(bh * 32 + jb) * 4096;
    ushortT* ol = KlG + (size_t)(bh * 32 + jb) * 4096;

#pragma unroll
    for (int i = 0; i < 2; i++) {
        const int s = tid + i * 256;          // slot 0..511
        const int f = s >> 6;                 // frag 0..7
        const int lane = s & 63;
        const int ds = f >> 1, kvt = f & 1;
        const int kv = kvt * 32 + (lane & 31);
        const int d0 = ds * 16 + (lane >> 5) * 8;
        ushortT hv[8], lv[8];
#pragma unroll
        for (int j = 0; j < 8; j++) split_tr(T[kv][d0 + j], hv[j], lv[j]);
        *(short4*)&oh[s * 8]     = *(short4*)&hv[0];
        *(short4*)&oh[s * 8 + 4] = *(short4*)&hv[4];
        *(short4*)&ol[s * 8]     = *(short4*)&lv[0];
        *(short4*)&ol[s * 8 + 4] = *(short4*)&lv[4];
    }
}

// ---------------------------------------------------------------------------
// Split-bf16 MFMA GEMM, 128x128 tile. z==2 (V projection) stores its output
// DIRECTLY as split-bf16 frag-major 32x32x16 V^T A-op tiles. z==0/1 fp32 rows.
// BK=64 + both-sides XOR swizzle (round-7) + XCD-chunked remap (round-8).
// launch_bounds (256,2): 2 blocks/CU. Round-9 verified configuration (286.8).
// Round-6 lesson: K-projection fusion here was net-negative; kv_convert kept.
// Round-10 lesson: 2-phase BK=32 dbuf regressed; 1-phase BK=64 is best here.
// Round-15 lesson: QBLK=64 attn (losing the pipeline) regressed 113->141.
// ---------------------------------------------------------------------------
__global__ __launch_bounds__(256, 2) void gemm_bt_split_kernel(
    const ushortT* __restrict__ Ah, const ushortT* __restrict__ Al,
    const ushortT* __restrict__ BtH, const ushortT* __restrict__ BtL,
    float* __restrict__ Y0, float* __restrict__ Y1,
    ushortT* __restrict__ VhG, ushortT* __restrict__ VlG)
{
    const int z = blockIdx.z;
    const ushortT* __restrict__ Bh = BtH + (size_t)z * 1024 * 1024;
    const ushortT* __restrict__ Bl = BtL + (size_t)z * 1024 * 1024;

    const int K = 1024, N = 1024;
    // XCD-chunked remap (bijective, grid 8x32 per z; 256%8==0):
    const int wid  = blockIdx.x + (blockIdx.y << 3);
    const int work = ((wid & 7) << 5) + (wid >> 3);
    const int m0 = (work >> 3) * 128;
    const int n0 = (work & 7) * 128;

    __shared__ __align__(16) ushortT AhS[128 * 64];
    __shared__ __align__(16) ushortT AlS[128 * 64];
    __shared__ __align__(16) ushortT BhS[128 * 64];
    __shared__ __align__(16) ushortT BlS[128 * 64];

    const int tid  = threadIdx.x;
    const int wave = tid >> 6, lane = tid & 63;
    const int quad = lane >> 4, l15 = lane & 15;
    const int wm = wave >> 1, wn = wave & 1;
    const int rx = l15 & 7;                 // read-side swizzle key

    float4v acc[4][4];
#pragma unroll
    for (int i = 0; i < 4; i++)
#pragma unroll
        for (int j = 0; j < 4; j++) acc[i][j] = (float4v){0.f, 0.f, 0.f, 0.f};

    for (int k0 = 0; k0 < K; k0 += 64) {
        __syncthreads();
#pragma unroll
        for (int i = 0; i < 4; i++) {
            const int s = tid + i * 256;    // slot 0..1023: row r = s>>3, blk = s&7
            const int r = s >> 3;
            // swizzle: LDS 16B-block (r, s&7) holds global k-block ((s&7) ^ (r&7))
            const int kk = ((s & 7) ^ (r & 7)) * 8;
            gld_lds16(Ah + (size_t)(m0 + r) * K + k0 + kk, &AhS[s * 8]);
            gld_lds16(Al + (size_t)(m0 + r) * K + k0 + kk, &AlS[s * 8]);
            gld_lds16(Bh + (size_t)(n0 + r) * K + k0 + kk, &BhS[s * 8]);
            gld_lds16(Bl + (size_t)(n0 + r) * K + k0 + kk, &BlS[s * 8]);
        }
        __syncthreads();

#pragma unroll
        for (int ks = 0; ks < 2; ks++) {
            FragU ah[4], al[4], bh[4], bl[4];
#pragma unroll
            for (int t = 0; t < 4; t++) {
                const int ra = wm * 64 + t * 16 + l15;   // ra&7 == rx
                const int rb = wn * 64 + t * 16 + l15;
                const int boff = ((ks * 4 + quad) ^ rx) * 8;
                ah[t].v = *(const short8v*)&AhS[ra * 64 + boff];
                al[t].v = *(const short8v*)&AlS[ra * 64 + boff];
                bh[t].v = *(const short8v*)&BhS[rb * 64 + boff];
                bl[t].v = *(const short8v*)&BlS[rb * 64 + boff];
            }
#pragma unroll
            for (int mt = 0; mt < 4; mt++)
#pragma unroll
                for (int nt = 0; nt < 4; nt++) {
                    acc[mt][nt] = __builtin_amdgcn_mfma_f32_16x16x32_bf16(ah[mt].v, bh[nt].v, acc[mt][nt], 0, 0, 0);
                    acc[mt][nt] = __builtin_amdgcn_mfma_f32_16x16x32_bf16(ah[mt].v, bl[nt].v, acc[mt][nt], 0, 0, 0);
                    acc[mt][nt] = __builtin_amdgcn_mfma_f32_16x16x32_bf16(al[mt].v, bh[nt].v, acc[mt][nt], 0, 0, 0);
                }
        }
    }

    if (z == 2) {
        // ---- V epilogue: direct frag-major split-bf16 V^T A-op tile store ----
        const int b  = m0 >> 11;
        const int jb = ((m0 & 2047) >> 6) + wm;
        const int h  = (n0 >> 6) + wn;
        const size_t tb = (size_t)((b * 16 + h) * 32 + jb) * 4096;
        ushortT* vh = VhG + tb;
        ushortT* vl = VlG + tb;
#pragma unroll
        for (int mt = 0; mt < 4; mt++)
#pragma unroll
            for (int nt = 0; nt < 4; nt++) {
                const int off = ((((nt >> 1) * 4 + mt) * 64 +
                                  (quad >> 1) * 32 + (nt & 1) * 16 + l15) * 8) +
                                (quad & 1) * 4;
                float4 vv = make_float4(acc[mt][nt][0], acc[mt][nt][1],
                                        acc[mt][nt][2], acc[mt][nt][3]);
                unsigned short h0, l0, h1, l1, h2, l2, h3, l3;
                split_tr(vv.x, h0, l0); split_tr(vv.y, h1, l1);
                split_tr(vv.z, h2, l2); split_tr(vv.w, h3, l3);
                *(short4*)&vh[off] = make_short4((short)h0, (short)h1, (short)h2, (short)h3);
                *(short4*)&vl[off] = make_short4((short)l0, (short)l1, (short)l2, (short)l3);
            }
    } else {
        float* __restrict__ Y = (z == 0) ? Y0 : Y1;
#pragma unroll
        for (int mt = 0; mt < 4; mt++)
#pragma unroll
            for (int r = 0; r < 4; r++) {
                const int row = m0 + wm * 64 + mt * 16 + quad * 4 + r;
                float* yp = Y + (size_t)row * N + n0 + wn * 64 + l15;
#pragma unroll
                for (int nt = 0; nt < 4; nt++)
                    yp[nt * 16] = acc[mt][nt][r];
            }
    }
}

// ---------------------------------------------------------------------------
// BM=64 x BN=128 split-bf16 GEMM for the OUTPUT PROJECTION (round-9 verified).
// 512 blocks = 2+/CU, LDS 48 KB, acc[4][2]. BK=64 1-phase + XOR swizzle +
// XCD-chunked remap. Bit-identical accumulation order vs 128^2 kernel.
// ---------------------------------------------------------------------------
__global__ __launch_bounds__(256, 2) void gemm_bt64_kernel(
    const ushortT* __restrict__ Ah, const ushortT* __restrict__ Al,
    const ushortT* __restrict__ Bh, const ushortT* __restrict__ Bl,
    float* __restrict__ Y)
{
    const int K = 1024, N = 1024;
    // grid 8 x 64 = 512; XCD-chunk: XCD x owns works [64x,64x+64) =
    // m-panels [8x,8x+8) -> A footprint 2MB L2-resident.
    const int wid  = blockIdx.x + (blockIdx.y << 3);
    const int work = ((wid & 7) << 6) + (wid >> 3);
    const int m0 = (work >> 3) * 64;
    const int n0 = (work & 7) * 128;

    __shared__ __align__(16) ushortT AhS[64 * 64];
    __shared__ __align__(16) ushortT AlS[64 * 64];
    __shared__ __align__(16) ushortT BhS[128 * 64];
    __shared__ __align__(16) ushortT BlS[128 * 64];

    const int tid  = threadIdx.x;
    const int wave = tid >> 6, lane = tid & 63;
    const int quad = lane >> 4, l15 = lane & 15;
    const int rx = l15 & 7;

    float4v acc[4][2];
#pragma unroll
    for (int i = 0; i < 4; i++)
#pragma unroll
        for (int j = 0; j < 2; j++) acc[i][j] = (float4v){0.f, 0.f, 0.f, 0.f};

    for (int k0 = 0; k0 < K; k0 += 64) {
        __syncthreads();
        // A: 512 slots (rows 0..63), B: 1024 slots (rows 0..127)
#pragma unroll
        for (int i = 0; i < 2; i++) {
            const int s = tid + i * 256;
            const int r = s >> 3;
            const int kk = ((s & 7) ^ (r & 7)) * 8;
            gld_lds16(Ah + (size_t)(m0 + r) * K + k0 + kk, &AhS[s * 8]);
            gld_lds16(Al + (size_t)(m0 + r) * K + k0 + kk, &AlS[s * 8]);
        }
#pragma unroll
        for (int i = 0; i < 4; i++) {
            const int s = tid + i * 256;
            const int r = s >> 3;
            const int kk = ((s & 7) ^ (r & 7)) * 8;
            gld_lds16(Bh + (size_t)(n0 + r) * K + k0 + kk, &BhS[s * 8]);
            gld_lds16(Bl + (size_t)(n0 + r) * K + k0 + kk, &BlS[s * 8]);
        }
        __syncthreads();

#pragma unroll
        for (int ks = 0; ks < 2; ks++) {
            FragU ah[4], al[4], bh[2], bl[2];
#pragma unroll
            for (int t = 0; t < 4; t++) {
                const int ra = t * 16 + l15;             // ra&7 == rx
                const int boff = ((ks * 4 + quad) ^ rx) * 8;
                ah[t].v = *(const short8v*)&AhS[ra * 64 + boff];
                al[t].v = *(const short8v*)&AlS[ra * 64 + boff];
            }
#pragma unroll
            for (int t = 0; t < 2; t++) {
                const int rb = wave * 32 + t * 16 + l15; // rb&7 == rx
                const int boff = ((ks * 4 + quad) ^ rx) * 8;
                bh[t].v = *(const short8v*)&BhS[rb * 64 + boff];
                bl[t].v = *(const short8v*)&BlS[rb * 64 + boff];
            }
#pragma unroll
            for (int mt = 0; mt < 4; mt++)
#pragma unroll
                for (int nt = 0; nt < 2; nt++) {
                    acc[mt][nt] = __builtin_amdgcn_mfma_f32_16x16x32_bf16(ah[mt].v, bh[nt].v, acc[mt][nt], 0, 0, 0);
                    acc[mt][nt] = __builtin_amdgcn_mfma_f32_16x16x32_bf16(ah[mt].v, bl[nt].v, acc[mt][nt], 0, 0, 0);
                    acc[mt][nt] = __builtin_amdgcn_mfma_f32_16x16x32_bf16(al[mt].v, bh[nt].v, acc[mt][nt], 0, 0, 0);
                }
        }
    }

#pragma unroll
    for (int mt = 0; mt < 4; mt++)
#pragma unroll
        for (int r = 0; r < 4; r++) {
            const int row = m0 + mt * 16 + quad * 4 + r;
            float* yp = Y + (size_t)row * N + n0 + wave * 32 + l15;
#pragma unroll
            for (int nt = 0; nt < 2; nt++)
                yp[nt * 16] = acc[mt][nt][r];
        }
}

// ---------------------------------------------------------------------------
// MFMA attention, 32x32x16. Round-8/9 verified configuration (113.7 µs,
// FETCH 24.7MB): 256 threads (4 waves), XCD-chunked remap (4 heads/XCD),
// W-form accumulator, round-4 software pipeline (QK(jb+1) issued before
// finish(jb); K staged 2-ahead, V 1-ahead; ONE barrier per iter).
// NO setprio (round-5: cost 2.9 µs). Per-step division is SEMANTIC (round-2);
// W-form carries it exactly: W_t = (al_t/l_{t-1})W_{t-1} + P_t V_t, O = W/l_T.
// Round-15 lesson: QBLK=64/2-wave blocks (dropping this pipeline) = +27 µs.
// ---------------------------------------------------------------------------
__global__ __launch_bounds__(256, 2) void attn_mfma_kernel(
    const float* __restrict__ q,
    const ushortT* __restrict__ KhG, const ushortT* __restrict__ KlG,
    const ushortT* __restrict__ VhG, const ushortT* __restrict__ VlG,
    ushortT* __restrict__ Oh, ushortT* __restrict__ Ol)
{
    // layout (ushort units): K0 @0, K1 @8192, V0 @16384, V1 @24576
    __shared__ __align__(16) ushortT SMEM[32768];   // 64 KiB

    const int tid  = threadIdx.x;
    const int wave = tid >> 6, lane = tid & 63;
    const int l31 = lane & 31, hi5 = lane >> 5;
    const int wid  = blockIdx.x + (blockIdx.y << 4);
    const int work = ((wid & 7) << 6) + (wid >> 3);
    const int qx = work & 15;
    const int bh = work >> 4;
    const int b = bh >> 4, h = bh & 15;
    const size_t base = (size_t)b * SS * DIM + (size_t)h * HD;
    const int qs0 = qx * 128 + wave * 32;
    const int lane8 = lane * 8;
    const int sl0 = wave * 128 + lane, sl1 = sl0 + 64;

    ushortT* K0 = SMEM;
    ushortT* K1 = SMEM + 8192;
    ushortT* V0 = SMEM + 16384;
    ushortT* V1 = SMEM + 24576;

    // ---- Q fragments (B-op: n = q = l31, k = d = ds*16 + hi5*8 + j) ----
    const float qscale = 0.125f * 1.4426950408889634f;
    FragU Qh[4], Ql[4];
    {
        const int qrow = qs0 + l31;
#pragma unroll
        for (int ds = 0; ds < 4; ds++) {
            const float* p0 = q + base + (size_t)qrow * DIM + ds * 16 + hi5 * 8;
            float4 a = *(const float4*)(p0);
            float4 c = *(const float4*)(p0 + 4);
            float e[8] = {a.x, a.y, a.z, a.w, c.x, c.y, c.z, c.w};
#pragma unroll
            for (int j = 0; j < 8; j++) {
                float x = e[j] * qscale;
                unsigned short hs = f2bf(x);
                Qh[ds].us[j] = hs;
                Ql[ds].us[j] = f2bf(x - bf2f(hs));
            }
        }
    }

    // W accumulators (= l_run * O): tile dt covers d = dt*32 + row, col q = l31
    float16v Oacc[2];
#pragma unroll
    for (int dt = 0; dt < 2; dt++)
        Oacc[dt] = (float16v){0.f,0.f,0.f,0.f,0.f,0.f,0.f,0.f,
                              0.f,0.f,0.f,0.f,0.f,0.f,0.f,0.f};

    float m_run = -INFINITY;
    float l_run = 0.f;
    float inv_prev = 1.0f;   // 1/l_{t-1}; arbitrary at t=0 (al=0 kills it)

    auto stage_K = [&](int t, ushortT* dst) {
        const size_t tb = (size_t)(bh * 32 + t) * 4096;
        gld_lds16(KhG + tb + sl0 * 8, &dst[sl0 * 8]);
        gld_lds16(KhG + tb + sl1 * 8, &dst[sl1 * 8]);
        gld_lds16(KlG + tb + sl0 * 8, &dst[4096 + sl0 * 8]);
        gld_lds16(KlG + tb + sl1 * 8, &dst[4096 + sl1 * 8]);
    };
    auto stage_V = [&](int t, ushortT* dst) {
        const size_t tb = (size_t)(bh * 32 + t) * 4096;
        gld_lds16(VhG + tb + sl0 * 8, &dst[sl0 * 8]);
        gld_lds16(VhG + tb + sl1 * 8, &dst[sl1 * 8]);
        gld_lds16(VlG + tb + sl0 * 8, &dst[4096 + sl0 * 8]);
        gld_lds16(VlG + tb + sl1 * 8, &dst[4096 + sl1 * 8]);
    };

    auto qk = [&](const ushortT* Kb, float16v (&st)[2]) {
        const ushortT* KhS = Kb;
        const ushortT* KlS = Kb + 4096;
#pragma unroll
        for (int t = 0; t < 2; t++)
            st[t] = (float16v){0.f,0.f,0.f,0.f,0.f,0.f,0.f,0.f,
                               0.f,0.f,0.f,0.f,0.f,0.f,0.f,0.f};
#pragma unroll
        for (int ds = 0; ds < 4; ds++) {
            FragU kh0, kl0, kh1, kl1;
            kh0.v = *(const short8v*)&KhS[(ds * 2 + 0) * 512 + lane8];
            kl0.v = *(const short8v*)&KlS[(ds * 2 + 0) * 512 + lane8];
            kh1.v = *(const short8v*)&KhS[(ds * 2 + 1) * 512 + lane8];
            kl1.v = *(const short8v*)&KlS[(ds * 2 + 1) * 512 + lane8];
            st[0] = __builtin_amdgcn_mfma_f32_32x32x16_bf16(kh0.v, Qh[ds].v, st[0], 0, 0, 0);
            st[0] = __builtin_amdgcn_mfma_f32_32x32x16_bf16(kh0.v, Ql[ds].v, st[0], 0, 0, 0);
            st[0] = __builtin_amdgcn_mfma_f32_32x32x16_bf16(kl0.v, Qh[ds].v, st[0], 0, 0, 0);
            st[1] = __builtin_amdgcn_mfma_f32_32x32x16_bf16(kh1.v, Qh[ds].v, st[1], 0, 0, 0);
            st[1] = __builtin_amdgcn_mfma_f32_32x32x16_bf16(kh1.v, Ql[ds].v, st[1], 0, 0, 0);
            st[1] = __builtin_amdgcn_mfma_f32_32x32x16_bf16(kl1.v, Qh[ds].v, st[1], 0, 0, 0);
        }
    };

    auto finish = [&](float16v (&st)[2], const ushortT* Vb) {
        const ushortT* VhS = Vb;
        const ushortT* VlS = Vb + 4096;
        float wscale;
        {
            float g[8];
#pragma unroll
            for (int t = 0; t < 2; t++)
#pragma unroll
                for (int i = 0; i < 4; i++)
                    g[t * 4 + i] = fmaxf(fmaxf(st[t][4 * i], st[t][4 * i + 1]),
                                         fmaxf(st[t][4 * i + 2], st[t][4 * i + 3]));
            float vmax = fmaxf(fmaxf(fmaxf(g[0], g[1]), fmaxf(g[2], g[3])),
                               fmaxf(fmaxf(g[4], g[5]), fmaxf(g[6], g[7])));
            vmax = fmaxf(vmax, __shfl_xor(vmax, 32, 64));
            const float mn = fmaxf(m_run, vmax);
            const float al = __builtin_amdgcn_exp2f(m_run - mn);   // 0 on first iter

            float ssum = 0.f;
#pragma unroll
            for (int t = 0; t < 2; t++)
#pragma unroll
                for (int r = 0; r < 16; r++) {
                    const float p = __builtin_amdgcn_exp2f(st[t][r] - mn);
                    st[t][r] = p;
                    ssum += p;
                }
            ssum += __shfl_xor(ssum, 32, 64);
            const float ln = al * l_run + ssum;
            wscale = al * inv_prev;          // al / l_{t-1}: carries prev division
            inv_prev = __builtin_amdgcn_rcpf(ln);
            m_run = mn;
            l_run = ln;
        }

#pragma unroll
        for (int dt = 0; dt < 2; dt++)
#pragma unroll
            for (int r = 0; r < 16; r++)
                Oacc[dt][r] *= wscale;

#pragma unroll
        for (int kvs = 0; kvs < 4; kvs++) {
            const int kvt = kvs >> 1;
            const int R = (kvs & 1) * 8;
            float p0 = st[kvt][R + 0], p1 = st[kvt][R + 1];
            float p2 = st[kvt][R + 2], p3 = st[kvt][R + 3];
            float p4 = st[kvt][R + 4], p5 = st[kvt][R + 5];
            float p6 = st[kvt][R + 6], p7 = st[kvt][R + 7];
            unsigned X0 = cvt_pk_bf16(p0, p1), X1 = cvt_pk_bf16(p2, p3);
            unsigned Y0 = cvt_pk_bf16(p4, p5), Y1 = cvt_pk_bf16(p6, p7);
            float e0 = p0 - __builtin_bit_cast(float, X0 << 16);
            float e1 = p1 - __builtin_bit_cast(float, X0 & 0xffff0000u);
            float e2 = p2 - __builtin_bit_cast(float, X1 << 16);
            float e3 = p3 - __builtin_bit_cast(float, X1 & 0xffff0000u);
            float e4 = p4 - __builtin_bit_cast(float, Y0 << 16);
            float e5 = p5 - __builtin_bit_cast(float, Y0 & 0xffff0000u);
            float e6 = p6 - __builtin_bit_cast(float, Y1 << 16);
            float e7 = p7 - __builtin_bit_cast(float, Y1 & 0xffff0000u);
            unsigned Z0 = cvt_pk_bf16(e0, e1), Z1 = cvt_pk_bf16(e2, e3);
            unsigned W0 = cvt_pk_bf16(e4, e5), W1 = cvt_pk_bf16(e6, e7);
            permlane32_swap(X0, Y0);
            permlane32_swap(X1, Y1);
            permlane32_swap(Z0, W0);
            permlane32_swap(Z1, W1);
            FragU Phf, Plf;
            Phf.u[0] = X0; Phf.u[1] = X1; Phf.u[2] = Y0; Phf.u[3] = Y1;
            Plf.u[0] = Z0; Plf.u[1] = Z1; Plf.u[2] = W0; Plf.u[3] = W1;

#pragma unroll
            for (int dt = 0; dt < 2; dt++) {
                FragU vh, vl;
                vh.v = *(const short8v*)&VhS[(dt * 4 + kvs) * 512 + lane8];
                vl.v = *(const short8v*)&VlS[(dt * 4 + kvs) * 512 + lane8];
                Oacc[dt] = __builtin_amdgcn_mfma_f32_32x32x16_bf16(vh.v, Phf.v, Oacc[dt], 0, 0, 0);
                Oacc[dt] = __builtin_amdgcn_mfma_f32_32x32x16_bf16(vl.v, Phf.v, Oacc[dt], 0, 0, 0);
                Oacc[dt] = __builtin_amdgcn_mfma_f32_32x32x16_bf16(vh.v, Plf.v, Oacc[dt], 0, 0, 0);
            }
        }
    };

    float16v stA[2], stB[2];

    // ---- prologue: publish K(0), K(1), V(0); compute S(0) ----
    stage_K(0, K0);
    stage_K(1, K1);
    stage_V(0, V0);
    __syncthreads();                 // vmcnt drain + publish K0,K1,V0
    qk(K0, stA);
    __syncthreads();                 // all waves done reading K0 (free for K(2))

    auto iter = [&](int jb, float16v (&SC)[2], float16v (&SN)[2],
                    ushortT* Kc, ushortT* Kn, ushortT* Vc, ushortT* Vn) {
        if (jb <= 29) stage_K(jb + 2, Kc);
        if (jb <= 30) stage_V(jb + 1, Vn);
        if (jb <= 30) qk(Kn, SN);    // MFMA on jb+1 — overlaps finish(jb)'s VALU
        finish(SC, Vc);              // stats+pack (VALU) + PV (MFMA) for jb
        __syncthreads();             // drains vmcnt; publishes K(jb+2), V(jb+1)
    };

    for (int jb = 0; jb < 32; jb += 2) {
        iter(jb,     stA, stB, K0, K1, V0, V1);
        iter(jb + 1, stB, stA, K1, K0, V1, V0);
    }

    // ---- deferred final division: O = W * (1/l_last) ----
#pragma unroll
    for (int dt = 0; dt < 2; dt++)
#pragma unroll
        for (int r = 0; r < 16; r++)
            Oacc[dt][r] *= inv_prev;

    // ---- epilogue: transpose O^T per tile via wave-local LDS (reuse SMEM),
    //      split-bf16 coalesced store ----
    float* EP = ((float*)SMEM) + wave * 1056;   // [32 q][33 f32] per wave
    const int qq = lane >> 1, dh = (lane & 1) * 16;
#pragma unroll
    for (int dt = 0; dt < 2; dt++) {
#pragma unroll
        for (int g = 0; g < 4; g++) {
            float4 wv = make_float4(Oacc[dt][4 * g + 0], Oacc[dt][4 * g + 1],
                                    Oacc[dt][4 * g + 2], Oacc[dt][4 * g + 3]);
            *(float4*)&EP[l31 * 33 + g * 8 + hi5 * 4] = wv;
        }
        // wave-local region: lgkmcnt orders write->read, no barrier
        float vals[16];
#pragma unroll
        for (int k4 = 0; k4 < 4; k4++)
            *(float4*)&vals[k4 * 4] = *(const float4*)&EP[qq * 33 + dh + k4 * 4];

        unsigned ho[8], lo8[8];
#pragma unroll
        for (int kk = 0; kk < 8; kk++) {
            unsigned short h0, l0, h1, l1;
            split_tr(vals[2 * kk], h0, l0);
            split_tr(vals[2 * kk + 1], h1, l1);
            ho[kk]  = (unsigned)h0 | ((unsigned)h1 << 16);
            lo8[kk] = (unsigned)l0 | ((unsigned)l1 << 16);
        }
        const int qrow = qs0 + qq;
        const size_t off = (size_t)(b * SS + qrow) * DIM + h * HD + dt * 32 + dh;
        *(uint4*)&Oh[off]     = make_uint4(ho[0], ho[1], ho[2], ho[3]);
        *(uint4*)&Oh[off + 8] = make_uint4(ho[4], ho[5], ho[6], ho[7]);
        *(uint4*)&Ol[off]     = make_uint4(lo8[0], lo8[1], lo8[2], lo8[3]);
        *(uint4*)&Ol[off + 8] = make_uint4(lo8[4], lo8[5], lo8[6], lo8[7]);
    }
}

// ---------------------------------------------------------------------------
extern "C" void kernel_launch(void* const* d_in, const int* in_sizes, int n_in,
                              void* d_out, int out_size, void* d_ws, size_t ws_size,
                              hipStream_t stream)
{
    const float* x  = (const float*)d_in[0];
    const float* Wq = (const float*)d_in[1];
    const float* Wk = (const float*)d_in[2];
    const float* Wv = (const float*)d_in[3];
    const float* Wo = (const float*)d_in[4];
    float* out = (float*)d_out;

    char* w = (char*)d_ws;
    float*   qw  = (float*)(w);                        // 16 MB
    float*   kw  = (float*)(w + ((size_t)16 << 20));   // 16 MB (later Oh/Ol)
    ushortT* VhG = (ushortT*)(w + ((size_t)32 << 20)); // 8 MB (V frag tiles, from GEMM)
    ushortT* VlG = (ushortT*)(w + ((size_t)40 << 20)); // 8 MB
    ushortT* XhS = (ushortT*)(w + ((size_t)48 << 20)); // 8 MB
    ushortT* XlS = (ushortT*)(w + ((size_t)56 << 20)); // 8 MB
    ushortT* WtH = (ushortT*)(w + ((size_t)64 << 20)); // 8 MB (4 matrices)
    ushortT* WtL = (ushortT*)(w + ((size_t)72 << 20)); // 8 MB
    ushortT* KhG = (ushortT*)(w + ((size_t)80 << 20)); // 8 MB
    ushortT* KlG = (ushortT*)(w + ((size_t)88 << 20)); // 8 MB  -> 96 MB total
    ushortT* OhS = (ushortT*)kw;                       // reuse after kv_convert
    ushortT* OlS = (ushortT*)(w + ((size_t)24 << 20));

    dim3 blk(256);
    const int n4 = MTOT * DIM / 4;

    // split X -> bf16 hi/lo; transpose+split all four W
    convert_split_kernel<<<dim3(n4 / 256), blk, 0, stream>>>(x, XhS, XlS, n4);
    transpose_split_kernel<<<dim3(16, 16, 4), blk, 0, stream>>>(Wq, Wk, Wv, Wo, WtH, WtL);

    // Q/K/V projections; z==2 (V) emits frag-major split tiles directly
    gemm_bt_split_kernel<<<dim3(8, 32, 3), blk, 0, stream>>>(
        XhS, XlS, WtH, WtL, qw, kw, VhG, VlG);

    // K -> frag-major split tiles (32x32x16 A-op layout)
    kv_convert_kernel<<<dim3(32, 32), blk, 0, stream>>>(kw, KhG, KlG);

    // attention (exact reference recurrence, kv block = 64)
    attn_mfma_kernel<<<dim3(16, 32), blk, 0, stream>>>(qw, KhG, KlG, VhG, VlG, OhS, OlS);

    // output projection: BM=64 tile, 512 blocks = 2+/CU
    gemm_bt64_kernel<<<dim3(8, 64), blk, 0, stream>>>(
        OhS, OlS, WtH + (size_t)3 * 1024 * 1024, WtL + (size_t)3 * 1024 * 1024,
        out);
}